// Round 5
// baseline (250.029 us; speedup 1.0000x reference)
//
#include <hip/hip_runtime.h>
#include <hip/hip_bf16.h>
#include <math.h>

// Problem dims
#define Bb 4
#define Sdim 2048
#define Ddim 512
#define RANK 32
#define Nn16 16
#define TOK (Bb * Sdim)   // 8192
#define NCh 64            // chunks along S
#define LCh (Sdim / NCh)  // 32 steps per chunk

using bf16x8 = __attribute__((ext_vector_type(8))) __bf16;
using f32x4  = __attribute__((ext_vector_type(4))) float;

__device__ __forceinline__ unsigned short f2bf(float f) {
    unsigned int u = __float_as_uint(f);
    u += 0x7fffu + ((u >> 16) & 1u);
    return (unsigned short)(u >> 16);
}

// async global->LDS, 16B per lane; lds base must be wave-uniform
#define GLD16(g, l) __builtin_amdgcn_global_load_lds( \
    (const __attribute__((address_space(1))) void*)(g), \
    (__attribute__((address_space(3))) void*)(l), 16, 0, 0)

__device__ __forceinline__ float softplus_f(float v) {
    return v > 20.f ? v : log1pf(__expf(v));
}

// ---------------------------------------------------------------------------
// P0: all weight transposes/casts in one launch. grid (16,16,4).
//  z=0: Wp [512][512] -> Wp_bf (row-major cast) + Wall rows [0,512) (Wp^T)
//  z=1: Wb [512][512] -> Wbt
//  z=2: Wdbc [512][64] -> Wdbct [64][512]   (only blockIdx.x<2 active)
//  z=3: Wdt [32][512]  -> Wdtt [512][32]    (only blockIdx.y==0 active)
// ---------------------------------------------------------------------------
__global__ void prep_transpose(const float* __restrict__ Wp, const float* __restrict__ Wb,
                               const float* __restrict__ Wdbc, const float* __restrict__ Wdt,
                               ushort* __restrict__ Wp_bf, ushort* __restrict__ Wall,
                               ushort* __restrict__ Wbt, ushort* __restrict__ Wdbct,
                               ushort* __restrict__ Wdtt) {
    __shared__ float t[32][33];
    int z = blockIdx.z;
    int bx = blockIdx.x * 32, by = blockIdx.y * 32;
    int x = threadIdx.x & 31, y = threadIdx.x >> 5;
    const float* in; ushort* outT; int K, N;
    if (z == 0)      { in = Wp;   outT = Wall;  K = 512; N = 512; }
    else if (z == 1) { in = Wb;   outT = Wbt;   K = 512; N = 512; }
    else if (z == 2) { if (bx >= 64) return; in = Wdbc; outT = Wdbct; K = 512; N = 64; }
    else             { if (by >= 32) return; in = Wdt;  outT = Wdtt;  K = 32;  N = 512; }
    #pragma unroll
    for (int yy = y; yy < 32; yy += 8) {
        float v = in[(size_t)(by + yy) * N + bx + x];
        t[yy][x] = v;
        if (z == 0) Wp_bf[(size_t)(by + yy) * N + bx + x] = f2bf(v);
    }
    __syncthreads();
    #pragma unroll
    for (int yy = y; yy < 32; yy += 8)
        outT[(size_t)(bx + yy) * K + by + x] = f2bf(t[x][yy]);
}

// ---------------------------------------------------------------------------
// bias folds. bias_all layout: [0,512)=bp, [512,1024)=bc, [1024,1536)=bdelta,
// [1536,1568)=bdbc2[32:64]
// ---------------------------------------------------------------------------
__global__ void bias_fold1(const float* __restrict__ bp, const float* __restrict__ Wb,
                           const float* __restrict__ bb, float* __restrict__ bias_all) {
    int j = blockIdx.x * 256 + threadIdx.x;    // grid 2 -> j<512
    float acc = bb[j];
    for (int k = 0; k < 512; ++k) acc = fmaf(bp[k], Wb[(size_t)k * 512 + j], acc);
    bias_all[j] = bp[j];
    bias_all[512 + j] = acc;
}

__global__ void bias_fold2(const float* __restrict__ Wdbc, const float* __restrict__ Wdt,
                           const float* __restrict__ b_dt, float* __restrict__ bias_all) {
    __shared__ float sbc[64];
    int tid = threadIdx.x;
    if (tid < 64) {
        float acc = 0.f;
        for (int k = 0; k < 512; ++k) acc = fmaf(bias_all[512 + k], Wdbc[(size_t)k * 64 + tid], acc);
        sbc[tid] = acc;
        if (tid >= 32) bias_all[1536 + tid - 32] = acc;
    }
    __syncthreads();
    #pragma unroll
    for (int rep = 0; rep < 2; ++rep) {
        int j = tid + rep * 256;
        float acc = b_dt[j];
        #pragma unroll
        for (int r = 0; r < 32; ++r) acc = fmaf(sbc[r], Wdt[(size_t)r * 512 + j], acc);
        bias_all[1024 + j] = acc;
    }
}

// ---------------------------------------------------------------------------
// P1: Wc = Wp @ Wb. A=Wp_bf [512][512], Bt=Wbt. Out: Wc_bf row-major +
// Wall rows [512,1024) = Wc^T. grid (4,4).
// ---------------------------------------------------------------------------
__global__ __launch_bounds__(256) void gemm_wc(
    const ushort* __restrict__ A, const ushort* __restrict__ Bt,
    ushort* __restrict__ Wc_bf, ushort* __restrict__ Wall)
{
    __shared__ __align__(16) ushort As[128 * 32];
    __shared__ __align__(16) ushort Bs[128 * 32];
    int tid = threadIdx.x, w = tid >> 6, lane = tid & 63;
    int bm = blockIdx.y * 128, bn = blockIdx.x * 128;
    int wm = (w & 1) * 64, wn = (w >> 1) * 64;
    int quad = lane >> 4, l16 = lane & 15;
    int srow = lane >> 2, schunk = (lane & 3) * 8;
    f32x4 acc[4][4] = {};
    for (int k0 = 0; k0 < 512; k0 += 32) {
        __syncthreads();
        #pragma unroll
        for (int s = 0; s < 2; ++s) {
            int r = w * 32 + s * 16;
            GLD16(A  + (size_t)(bm + r + srow) * 512 + k0 + schunk, &As[r * 32]);
            GLD16(Bt + (size_t)(bn + r + srow) * 512 + k0 + schunk, &Bs[r * 32]);
        }
        __syncthreads();
        bf16x8 af[4], bfr[4];
        #pragma unroll
        for (int i = 0; i < 4; ++i)
            af[i] = *(const bf16x8*)(const void*)&As[(wm + 16 * i + l16) * 32 + quad * 8];
        #pragma unroll
        for (int j = 0; j < 4; ++j)
            bfr[j] = *(const bf16x8*)(const void*)&Bs[(wn + 16 * j + l16) * 32 + quad * 8];
        #pragma unroll
        for (int i = 0; i < 4; ++i)
            #pragma unroll
            for (int j = 0; j < 4; ++j)
                acc[i][j] = __builtin_amdgcn_mfma_f32_16x16x32_bf16(af[i], bfr[j], acc[i][j], 0, 0, 0);
    }
    #pragma unroll
    for (int i = 0; i < 4; ++i) {
        int row = bm + wm + 16 * i + quad * 4;
        #pragma unroll
        for (int j = 0; j < 4; ++j) {
            int col = bn + wn + 16 * j + l16;
            #pragma unroll
            for (int r = 0; r < 4; ++r) {
                ushort v = f2bf(acc[i][j][r]);
                Wc_bf[(size_t)(row + r) * 512 + col] = v;
                Wall[(size_t)(512 + col) * 512 + row + r] = v;   // Wc^T
            }
        }
    }
}

// ---------------------------------------------------------------------------
// P2: Wdbc2 = Wc @ Wdbc. A=Wc_bf [512][512], Bt=Wdbct [64][512]. M=512,N=64.
// Out: Wdbc2_rm [512][64] bf16 + Wall rows [1536,1568) = Wdbc2[:,32:64]^T.
// grid (1,4).
// ---------------------------------------------------------------------------
__global__ __launch_bounds__(256) void gemm_wdbc2(
    const ushort* __restrict__ A, const ushort* __restrict__ Bt,
    ushort* __restrict__ Wdbc2_rm, ushort* __restrict__ Wall)
{
    __shared__ __align__(16) ushort As[128 * 32];
    __shared__ __align__(16) ushort Bs[64 * 32];
    int tid = threadIdx.x, w = tid >> 6, lane = tid & 63;
    int bm = blockIdx.y * 128;
    int wm = w * 32;
    int quad = lane >> 4, l16 = lane & 15;
    int srow = lane >> 2, schunk = (lane & 3) * 8;
    f32x4 acc[2][4] = {};
    for (int k0 = 0; k0 < 512; k0 += 32) {
        __syncthreads();
        #pragma unroll
        for (int s = 0; s < 2; ++s) {
            int r = w * 32 + s * 16;
            GLD16(A + (size_t)(bm + r + srow) * 512 + k0 + schunk, &As[r * 32]);
        }
        {
            int r = w * 16;
            GLD16(Bt + (size_t)(r + srow) * 512 + k0 + schunk, &Bs[r * 32]);
        }
        __syncthreads();
        bf16x8 af[2], bfr[4];
        #pragma unroll
        for (int i = 0; i < 2; ++i)
            af[i] = *(const bf16x8*)(const void*)&As[(wm + 16 * i + l16) * 32 + quad * 8];
        #pragma unroll
        for (int j = 0; j < 4; ++j)
            bfr[j] = *(const bf16x8*)(const void*)&Bs[(16 * j + l16) * 32 + quad * 8];
        #pragma unroll
        for (int i = 0; i < 2; ++i)
            #pragma unroll
            for (int j = 0; j < 4; ++j)
                acc[i][j] = __builtin_amdgcn_mfma_f32_16x16x32_bf16(af[i], bfr[j], acc[i][j], 0, 0, 0);
    }
    #pragma unroll
    for (int i = 0; i < 2; ++i) {
        int row = bm + wm + 16 * i + quad * 4;
        #pragma unroll
        for (int j = 0; j < 4; ++j) {
            int col = 16 * j + l16;
            #pragma unroll
            for (int r = 0; r < 4; ++r) {
                ushort v = f2bf(acc[i][j][r]);
                Wdbc2_rm[(size_t)(row + r) * 64 + col] = v;
                if (col >= 32)
                    Wall[(size_t)(1536 + col - 32) * 512 + row + r] = v;
            }
        }
    }
}

// ---------------------------------------------------------------------------
// P3: Wdelta^T = Wdt^T @ (Wdbc2[:,:32])^T. A=Wdtt [512][32], Bt=Wdbc2_rm
// (stride 64, first 32 cols). K=32 single MFMA step. Out: Wall rows
// [1024,1536): Wall[(1024+j)*512+d] = Wdelta[d][j]. grid (4,4).
// ---------------------------------------------------------------------------
__global__ __launch_bounds__(256) void gemm_wdelta(
    const ushort* __restrict__ A, const ushort* __restrict__ Bt,
    ushort* __restrict__ Wall)
{
    __shared__ __align__(16) ushort As[128 * 32];
    __shared__ __align__(16) ushort Bs[128 * 32];
    int tid = threadIdx.x, w = tid >> 6, lane = tid & 63;
    int bm = blockIdx.y * 128, bn = blockIdx.x * 128;
    int wm = (w & 1) * 64, wn = (w >> 1) * 64;
    int quad = lane >> 4, l16 = lane & 15;
    int srow = lane >> 2, schunk = (lane & 3) * 8;
    #pragma unroll
    for (int s = 0; s < 2; ++s) {
        int r = w * 32 + s * 16;
        GLD16(A  + (size_t)(bm + r + srow) * 32 + schunk, &As[r * 32]);
        GLD16(Bt + (size_t)(bn + r + srow) * 64 + schunk, &Bs[r * 32]);
    }
    __syncthreads();
    bf16x8 af[4], bfr[4];
    #pragma unroll
    for (int i = 0; i < 4; ++i)
        af[i] = *(const bf16x8*)(const void*)&As[(wm + 16 * i + l16) * 32 + quad * 8];
    #pragma unroll
    for (int j = 0; j < 4; ++j)
        bfr[j] = *(const bf16x8*)(const void*)&Bs[(wn + 16 * j + l16) * 32 + quad * 8];
    f32x4 acc[4][4] = {};
    #pragma unroll
    for (int i = 0; i < 4; ++i)
        #pragma unroll
        for (int j = 0; j < 4; ++j)
            acc[i][j] = __builtin_amdgcn_mfma_f32_16x16x32_bf16(af[i], bfr[j], acc[i][j], 0, 0, 0);
    #pragma unroll
    for (int i = 0; i < 4; ++i) {
        int row = bm + wm + 16 * i + quad * 4;
        #pragma unroll
        for (int j = 0; j < 4; ++j) {
            int col = bn + wn + 16 * j + l16;
            #pragma unroll
            for (int r = 0; r < 4; ++r)
                Wall[(size_t)(1024 + row + r) * 512 + col] = f2bf(acc[i][j][r]);
        }
    }
}

// ---------------------------------------------------------------------------
// LayerNorm -> bf16. One wave per row of 512, 4 rows / 256-thr block.
// ---------------------------------------------------------------------------
__global__ void ln_kernel(const float* __restrict__ x, const float* __restrict__ gamma,
                          const float* __restrict__ beta, ushort* __restrict__ xn) {
    int row = blockIdx.x * 4 + (threadIdx.x >> 6);
    int lane = threadIdx.x & 63;
    const float4* xr = (const float4*)(x + (size_t)row * Ddim);
    float4 v0 = xr[lane];
    float4 v1 = xr[lane + 64];
    float s = v0.x + v0.y + v0.z + v0.w + v1.x + v1.y + v1.z + v1.w;
    float q = v0.x*v0.x + v0.y*v0.y + v0.z*v0.z + v0.w*v0.w
            + v1.x*v1.x + v1.y*v1.y + v1.z*v1.z + v1.w*v1.w;
    #pragma unroll
    for (int m = 1; m <= 32; m <<= 1) { s += __shfl_xor(s, m); q += __shfl_xor(q, m); }
    float mu = s * (1.0f / Ddim);
    float var = q * (1.0f / Ddim) - mu * mu;
    float rs = rsqrtf(var + 1e-5f);
    const float4* g4 = (const float4*)gamma;
    const float4* b4 = (const float4*)beta;
    float4 g0 = g4[lane], g1 = g4[lane + 64];
    float4 be0 = b4[lane], be1 = b4[lane + 64];
    ushort4 u0, u1;
    u0.x = f2bf((v0.x - mu) * rs * g0.x + be0.x);
    u0.y = f2bf((v0.y - mu) * rs * g0.y + be0.y);
    u0.z = f2bf((v0.z - mu) * rs * g0.z + be0.z);
    u0.w = f2bf((v0.w - mu) * rs * g0.w + be0.w);
    u1.x = f2bf((v1.x - mu) * rs * g1.x + be1.x);
    u1.y = f2bf((v1.y - mu) * rs * g1.y + be1.y);
    u1.z = f2bf((v1.z - mu) * rs * g1.z + be1.z);
    u1.w = f2bf((v1.w - mu) * rs * g1.w + be1.w);
    *(ushort4*)(xn + (size_t)row * Ddim + lane * 4) = u0;
    *(ushort4*)(xn + (size_t)row * Ddim + 256 + lane * 4) = u1;
}

// ---------------------------------------------------------------------------
// MEGA GEMM: [z1 | bwd | delta(softplus) | BC] = xn @ Wall + bias_all.
// Wall rows: [0,512)=Wp^T, [512,1024)=Wc^T, [1024,1536)=Wdelta^T,
// [1536,1568)=Wdbc2[:,32:64]^T. grid (13, 64): tiles 0..11 are 128-wide,
// tile 12 is the 32-wide BC tile.
// ---------------------------------------------------------------------------
__global__ __launch_bounds__(256) void gemm_mega(
    const ushort* __restrict__ A, const ushort* __restrict__ Wall,
    const float* __restrict__ bias_all,
    float* __restrict__ z1, float* bwdout, float* __restrict__ delta,
    float* __restrict__ BC)
{
    __shared__ __align__(16) ushort As[128 * 32];
    __shared__ __align__(16) ushort Bs[128 * 32];
    int tid = threadIdx.x, w = tid >> 6, lane = tid & 63;
    int bm = blockIdx.y * 128;
    int bt = blockIdx.x;
    int quad = lane >> 4, l16 = lane & 15;
    int srow = lane >> 2, schunk = (lane & 3) * 8;

    if (bt < 12) {
        int bn = bt * 128;
        int wm = (w & 1) * 64, wn = (w >> 1) * 64;
        f32x4 acc[4][4] = {};
        for (int k0 = 0; k0 < 512; k0 += 32) {
            __syncthreads();
            #pragma unroll
            for (int s = 0; s < 2; ++s) {
                int r = w * 32 + s * 16;
                GLD16(A    + (size_t)(bm + r + srow) * 512 + k0 + schunk, &As[r * 32]);
                GLD16(Wall + (size_t)(bn + r + srow) * 512 + k0 + schunk, &Bs[r * 32]);
            }
            __syncthreads();
            bf16x8 af[4], bfr[4];
            #pragma unroll
            for (int i = 0; i < 4; ++i)
                af[i] = *(const bf16x8*)(const void*)&As[(wm + 16 * i + l16) * 32 + quad * 8];
            #pragma unroll
            for (int j = 0; j < 4; ++j)
                bfr[j] = *(const bf16x8*)(const void*)&Bs[(wn + 16 * j + l16) * 32 + quad * 8];
            #pragma unroll
            for (int i = 0; i < 4; ++i)
                #pragma unroll
                for (int j = 0; j < 4; ++j)
                    acc[i][j] = __builtin_amdgcn_mfma_f32_16x16x32_bf16(af[i], bfr[j], acc[i][j], 0, 0, 0);
        }
        int reg = bn >> 9;                       // 0=z1, 1=bwd, 2=delta
        float* obase = (reg == 0) ? z1 : (reg == 1) ? bwdout : delta;
        #pragma unroll
        for (int i = 0; i < 4; ++i) {
            int row = bm + wm + 16 * i + quad * 4;
            #pragma unroll
            for (int j = 0; j < 4; ++j) {
                int gcol = bn + wn + 16 * j + l16;
                int lcol = gcol - (reg << 9);
                float bv = bias_all[gcol];
                #pragma unroll
                for (int r = 0; r < 4; ++r) {
                    float v = acc[i][j][r] + bv;
                    if (reg == 2) v = softplus_f(v);
                    obase[(size_t)(row + r) * 512 + lcol] = v;
                }
            }
        }
    } else {
        // BC tile: 32 cols (Wall rows 1536..1567)
        int wm = w * 32;
        f32x4 acc[2][2] = {};
        for (int k0 = 0; k0 < 512; k0 += 32) {
            __syncthreads();
            #pragma unroll
            for (int s = 0; s < 2; ++s) {
                int r = w * 32 + s * 16;
                GLD16(A + (size_t)(bm + r + srow) * 512 + k0 + schunk, &As[r * 32]);
            }
            if (w < 2) {
                int r = w * 16;
                GLD16(Wall + (size_t)(1536 + r + srow) * 512 + k0 + schunk, &Bs[r * 32]);
            }
            __syncthreads();
            bf16x8 af[2], bfr[2];
            #pragma unroll
            for (int i = 0; i < 2; ++i)
                af[i] = *(const bf16x8*)(const void*)&As[(wm + 16 * i + l16) * 32 + quad * 8];
            #pragma unroll
            for (int j = 0; j < 2; ++j)
                bfr[j] = *(const bf16x8*)(const void*)&Bs[(16 * j + l16) * 32 + quad * 8];
            #pragma unroll
            for (int i = 0; i < 2; ++i)
                #pragma unroll
                for (int j = 0; j < 2; ++j)
                    acc[i][j] = __builtin_amdgcn_mfma_f32_16x16x32_bf16(af[i], bfr[j], acc[i][j], 0, 0, 0);
        }
        #pragma unroll
        for (int i = 0; i < 2; ++i) {
            int row = bm + wm + 16 * i + quad * 4;
            #pragma unroll
            for (int j = 0; j < 2; ++j) {
                int col = 16 * j + l16;
                float bv = bias_all[1536 + col];
                #pragma unroll
                for (int r = 0; r < 4; ++r)
                    BC[(size_t)(row + r) * 32 + col] = acc[i][j][r] + bv;
            }
        }
    }
}

// ---------------------------------------------------------------------------
// Chunked parallel scan. BC array is [TOK][32]: cols 0..15 = B, 16..31 = C.
// ---------------------------------------------------------------------------
__global__ __launch_bounds__(256) void scan_pass1(
    const float* __restrict__ delta, const float* __restrict__ bwd,
    const float* __restrict__ BC, const float* __restrict__ A_log,
    float* __restrict__ hend, float* __restrict__ sdbuf)
{
    int d = (blockIdx.x << 8) + threadIdx.x;
    int c = blockIdx.y;
    int b = blockIdx.z;

    float A[16];
    {
        const float4* al = (const float4*)(A_log + (size_t)d * 16);
        #pragma unroll
        for (int i = 0; i < 4; ++i) {
            float4 v = al[i];
            A[4*i+0] = -__expf(v.x); A[4*i+1] = -__expf(v.y);
            A[4*i+2] = -__expf(v.z); A[4*i+3] = -__expf(v.w);
        }
    }
    float h[16];
    #pragma unroll
    for (int n = 0; n < 16; ++n) h[n] = 0.f;
    float sd = 0.f;

    size_t base = ((size_t)(b * Sdim + c * LCh)) * Ddim + d;
    const float* bcrow = BC + ((size_t)(b * Sdim + c * LCh)) * 32;

    #pragma unroll 2
    for (int i = 0; i < LCh; ++i) {
        float dlt = delta[base + (size_t)i * Ddim];
        float bw  = bwd [base + (size_t)i * Ddim];
        float4 B0 = *(const float4*)(bcrow + i * 32 + 0);
        float4 B1 = *(const float4*)(bcrow + i * 32 + 4);
        float4 B2 = *(const float4*)(bcrow + i * 32 + 8);
        float4 B3 = *(const float4*)(bcrow + i * 32 + 12);
        sd += dlt;
        float xb = dlt * bw;
        float Bv[16] = {B0.x,B0.y,B0.z,B0.w, B1.x,B1.y,B1.z,B1.w,
                        B2.x,B2.y,B2.z,B2.w, B3.x,B3.y,B3.z,B3.w};
        #pragma unroll
        for (int n = 0; n < 16; ++n)
            h[n] = fmaf(__expf(dlt * A[n]), h[n], xb * Bv[n]);
    }
    size_t cidx = ((((size_t)b * NCh + c) * Ddim) + d) * 16;
    float4* ho = (float4*)(hend + cidx);
    ho[0] = make_float4(h[0],  h[1],  h[2],  h[3]);
    ho[1] = make_float4(h[4],  h[5],  h[6],  h[7]);
    ho[2] = make_float4(h[8],  h[9],  h[10], h[11]);
    ho[3] = make_float4(h[12], h[13], h[14], h[15]);
    sdbuf[((size_t)b * NCh + c) * Ddim + d] = sd;
}

// carry combine, 8-wide batches (loads+exp independent of hin; only fma chains)
__global__ __launch_bounds__(256) void scan_pass2(
    float* __restrict__ hend, const float* __restrict__ sdbuf,
    const float* __restrict__ A_log)
{
    int gl = blockIdx.x * 256 + threadIdx.x;
    int b = gl >> 13;
    int r = gl & 8191;
    int d = r >> 4;
    float A = -__expf(A_log[r]);
    float hin = 0.f;
    for (int c0 = 0; c0 < NCh; c0 += 8) {
        float he[8], dec[8];
        #pragma unroll
        for (int u = 0; u < 8; ++u) {
            size_t idx = (((size_t)b * NCh + c0 + u) * Ddim) * 16 + r;
            he[u]  = hend[idx];
            dec[u] = __expf(A * sdbuf[((size_t)b * NCh + c0 + u) * Ddim + d]);
        }
        #pragma unroll
        for (int u = 0; u < 8; ++u) {
            size_t idx = (((size_t)b * NCh + c0 + u) * Ddim) * 16 + r;
            hend[idx] = hin;
            hin = fmaf(dec[u], hin, he[u]);
        }
    }
}

// bwd/out alias (bwd lives in d_out); read-before-write per exclusive (t,d).
__global__ __launch_bounds__(256) void scan_pass3(
    const float* __restrict__ delta, const float* bwd,
    const float* __restrict__ BC, const float* __restrict__ z1,
    const float* __restrict__ x, const float* __restrict__ A_log,
    const float* __restrict__ D_ssm, const float* __restrict__ hin,
    float* out)
{
    int d = (blockIdx.x << 8) + threadIdx.x;
    int c = blockIdx.y;
    int b = blockIdx.z;

    float A[16];
    {
        const float4* al = (const float4*)(A_log + (size_t)d * 16);
        #pragma unroll
        for (int i = 0; i < 4; ++i) {
            float4 v = al[i];
            A[4*i+0] = -__expf(v.x); A[4*i+1] = -__expf(v.y);
            A[4*i+2] = -__expf(v.z); A[4*i+3] = -__expf(v.w);
        }
    }
    float h[16];
    {
        size_t cidx = ((((size_t)b * NCh + c) * Ddim) + d) * 16;
        const float4* hi = (const float4*)(hin + cidx);
        float4 h0 = hi[0], h1 = hi[1], h2 = hi[2], h3 = hi[3];
        h[0]=h0.x; h[1]=h0.y; h[2]=h0.z; h[3]=h0.w;
        h[4]=h1.x; h[5]=h1.y; h[6]=h1.z; h[7]=h1.w;
        h[8]=h2.x; h[9]=h2.y; h[10]=h2.z; h[11]=h2.w;
        h[12]=h3.x; h[13]=h3.y; h[14]=h3.z; h[15]=h3.w;
    }
    float Dd = D_ssm[d];

    size_t base = ((size_t)(b * Sdim + c * LCh)) * Ddim + d;
    const float* bcrow = BC + ((size_t)(b * Sdim + c * LCh)) * 32;

    #pragma unroll 2
    for (int i = 0; i < LCh; ++i) {
        float dlt = delta[base + (size_t)i * Ddim];
        float bw  = bwd [base + (size_t)i * Ddim];
        float z1v = z1  [base + (size_t)i * Ddim];
        float xv  = x   [base + (size_t)i * Ddim];
        float4 B0 = *(const float4*)(bcrow + i * 32 + 0);
        float4 B1 = *(const float4*)(bcrow + i * 32 + 4);
        float4 B2 = *(const float4*)(bcrow + i * 32 + 8);
        float4 B3 = *(const float4*)(bcrow + i * 32 + 12);
        float4 C0 = *(const float4*)(bcrow + i * 32 + 16);
        float4 C1 = *(const float4*)(bcrow + i * 32 + 20);
        float4 C2 = *(const float4*)(bcrow + i * 32 + 24);
        float4 C3 = *(const float4*)(bcrow + i * 32 + 28);
        float Bv[16] = {B0.x,B0.y,B0.z,B0.w, B1.x,B1.y,B1.z,B1.w,
                        B2.x,B2.y,B2.z,B2.w, B3.x,B3.y,B3.z,B3.w};
        float Cv[16] = {C0.x,C0.y,C0.z,C0.w, C1.x,C1.y,C1.z,C1.w,
                        C2.x,C2.y,C2.z,C2.w, C3.x,C3.y,C3.z,C3.w};
        float xb = dlt * bw;
        float y  = Dd * bw;
        #pragma unroll
        for (int n = 0; n < 16; ++n) {
            h[n] = fmaf(__expf(dlt * A[n]), h[n], xb * Bv[n]);
            y = fmaf(h[n], Cv[n], y);
        }
        float silu = z1v / (1.f + __expf(-z1v));
        out[base + (size_t)i * Ddim] = fmaf(z1v + y, silu, xv);
    }
}

// ---------------------------------------------------------------------------
extern "C" void kernel_launch(void* const* d_in, const int* in_sizes, int n_in,
                              void* d_out, int out_size, void* d_ws, size_t ws_size,
                              hipStream_t stream) {
    const float* x      = (const float*)d_in[0];
    const float* gamma  = (const float*)d_in[1];
    const float* beta   = (const float*)d_in[2];
    const float* W_proj = (const float*)d_in[3];
    const float* b_proj = (const float*)d_in[4];
    // d_in[5]=W_fwd, d_in[6]=b_fwd dead in reference (x1_ssm unused)
    const float* W_bwd  = (const float*)d_in[7];
    const float* b_bwd  = (const float*)d_in[8];
    const float* W_dbc  = (const float*)d_in[9];
    const float* W_dt   = (const float*)d_in[10];
    const float* b_dt   = (const float*)d_in[11];
    const float* A_log  = (const float*)d_in[12];
    const float* D_ssm  = (const float*)d_in[13];
    float* out = (float*)d_out;

    char* p = (char*)d_ws;
    ushort* xn_bf    = (ushort*)p;                        // 8 MB   [0,8M)
    float*  z1       = (float*)(p + (8ull  << 20));       // 16 MB  [8,24M)
    float*  delta    = (float*)(p + (24ull << 20));       // 16 MB  [24,40M)
    float*  BC       = (float*)(p + (40ull << 20));       // 1 MB   [40,41M)
    float*  hend     = (float*)(p + (41ull << 20));       // 8 MB   [41,49M)
    float*  sdbuf    = (float*)(p + (49ull << 20));       // 512 KB
    ushort* Wall     = (ushort*)(p + (50ull << 20));      // 1568*512*2 = 1.53 MB
    ushort* Wp_bf    = (ushort*)(p + (52ull << 20));      // 512 KB
    ushort* Wbt      = Wp_bf + (size_t)512 * 512;         // 512 KB
    ushort* Wc_bf    = Wbt   + (size_t)512 * 512;         // 512 KB
    ushort* Wdbct    = Wc_bf + (size_t)512 * 512;         // 64 KB
    ushort* Wdtt     = Wdbct + (size_t)64 * 512;          // 32 KB
    ushort* Wdbc2_rm = Wdtt  + (size_t)512 * 32;          // 64 KB
    float*  bias_all = (float*)(Wdbc2_rm + (size_t)512 * 64);  // 6.3 KB
    float*  bwd      = out;                               // bwd lives in d_out

    // --- weight folding (tiny, once per call) ---
    prep_transpose<<<dim3(16, 16, 4), dim3(256), 0, stream>>>(
        W_proj, W_bwd, W_dbc, W_dt, Wp_bf, Wall, Wbt, Wdbct, Wdtt);
    bias_fold1<<<dim3(2), dim3(256), 0, stream>>>(b_proj, W_bwd, b_bwd, bias_all);
    bias_fold2<<<dim3(1), dim3(256), 0, stream>>>(W_dbc, W_dt, b_dt, bias_all);
    gemm_wc<<<dim3(4, 4), dim3(256), 0, stream>>>(Wp_bf, Wbt, Wc_bf, Wall);
    gemm_wdbc2<<<dim3(1, 4), dim3(256), 0, stream>>>(Wc_bf, Wdbct, Wdbc2_rm, Wall);
    gemm_wdelta<<<dim3(4, 4), dim3(256), 0, stream>>>(Wdtt, Wdbc2_rm, Wall);

    // --- main path ---
    ln_kernel<<<dim3(TOK / 4), dim3(256), 0, stream>>>(x, gamma, beta, xn_bf);
    gemm_mega<<<dim3(13, TOK / 128), dim3(256), 0, stream>>>(
        xn_bf, Wall, bias_all, z1, bwd, delta, BC);
    scan_pass1<<<dim3(2, NCh, Bb), dim3(256), 0, stream>>>(delta, bwd, BC, A_log, hend, sdbuf);
    scan_pass2<<<dim3(Bb * Ddim * Nn16 / 256), dim3(256), 0, stream>>>(hend, sdbuf, A_log);
    scan_pass3<<<dim3(2, NCh, Bb), dim3(256), 0, stream>>>(delta, bwd, BC, z1, x, A_log, D_ssm, hend, out);
}